// Round 6
// baseline (317.207 us; speedup 1.0000x reference)
//
#include <hip/hip_runtime.h>
#include <hip/hip_bf16.h>

#define B_  16
#define G_  4
#define CG  64
#define H_  64
#define W_  64
#define KK  9
#define HW  (H_ * W_)
#define PD  68            // padded spatial dim (64 + 2 each side)
#define XSLICE (PD * PD * CG)   // shorts per (b,g) slice of xTpad

typedef short  short8  __attribute__((ext_vector_type(8)));
typedef float  f32x4   __attribute__((ext_vector_type(4)));

__device__ __forceinline__ short f2bf(float v) {
    __hip_bfloat16 hb = __float2bfloat16(v);
    short s;
    __builtin_memcpy(&s, &hb, 2);
    return s;
}

// unpack a u32 holding two bf16 (ch 2j low, 2j+1 high) into float2
__device__ __forceinline__ float2 up2(unsigned int u) {
    union { unsigned int i; float f; } lo, hi;
    lo.i = u << 16;
    hi.i = u & 0xffff0000u;
    return make_float2(lo.f, hi.f);
}

// bilinear combine of 2 packed channels, repacked to 2 bf16 in a u32
__device__ __forceinline__ unsigned int interp2(unsigned int c00, unsigned int c01,
                                                unsigned int c10, unsigned int c11,
                                                float2 w00, float2 w01,
                                                float2 w10, float2 w11) {
    float2 r = up2(c00) * w00 + up2(c01) * w01 + up2(c10) * w10 + up2(c11) * w11;
    __hip_bfloat162 h = __float22bfloat162_rn(r);
    unsigned int o;
    __builtin_memcpy(&o, &h, 4);
    return o;
}

// interp of 8 channels (4 packed u32) -> short8 B-fragment
__device__ __forceinline__ short8 interp8(uint4 a, uint4 b, uint4 c, uint4 d,
                                          float2 w00, float2 w01,
                                          float2 w10, float2 w11) {
    uint4 r;
    r.x = interp2(a.x, b.x, c.x, d.x, w00, w01, w10, w11);
    r.y = interp2(a.y, b.y, c.y, d.y, w00, w01, w10, w11);
    r.z = interp2(a.z, b.z, c.z, d.z, w00, w01, w10, w11);
    r.w = interp2(a.w, b.w, c.w, d.w, w00, w01, w10, w11);
    short8 s;
    __builtin_memcpy(&s, &r, 16);
    return s;
}

// ---------------------------------------------------------------------------
// Merged prep kernel.
//  blocks [0, 64*68): x -> xTpad[bg][yp][xp][i] bf16, zero borders (pad 2)
//  blocks [64*68, +864): weight prep
//   dwE[g][k][ot][kh][q][nn][e] bf16 = def_w[g][ot*16+nn][kh*32+q*8+e][k]
//   owA[g][s][tm][q][jj][e]     bf16 = off_w[g][tm*16+jj][(s&1)*32+q*8+e][s>>1]
// ---------------------------------------------------------------------------
__global__ void prep_all(const float* __restrict__ x,
                         const float* __restrict__ off_w,
                         const float* __restrict__ def_w,
                         short* __restrict__ xTpad,
                         short* __restrict__ dwE,
                         short* __restrict__ owA)
{
    const int blk = blockIdx.x;
    const int t   = threadIdx.x;
    __shared__ float sRow[CG][65];

    if (blk < 64 * PD) {
        const int yp = blk % PD;
        const int bg = blk / PD;
        short* dst = xTpad + (size_t)bg * XSLICE + (size_t)yp * PD * CG;

        if (yp < 2 || yp >= 66) {
            const int4 z = {0, 0, 0, 0};
            for (int c = t; c < (PD * CG * 2) / 16; c += 256)
                ((int4*)dst)[c] = z;
            return;
        }

        const int yy = yp - 2;
        const float* src = x + (size_t)bg * CG * HW + (size_t)yy * W_;
        {
            const int i  = t >> 2;
            const int x0 = (t & 3) * 16;
            const float* sp = src + (size_t)i * HW + x0;
#pragma unroll
            for (int c = 0; c < 4; c++) {
                const float4 v = ((const float4*)sp)[c];
                sRow[i][x0 + c * 4 + 0] = v.x;
                sRow[i][x0 + c * 4 + 1] = v.y;
                sRow[i][x0 + c * 4 + 2] = v.z;
                sRow[i][x0 + c * 4 + 3] = v.w;
            }
        }
        __syncthreads();

        for (int task = t; task < PD * 8; task += 256) {
            const int ich = task & 7;
            const int xp  = task >> 3;
            const int xx  = xp - 2;
            short8 v = {0, 0, 0, 0, 0, 0, 0, 0};
            if ((unsigned)xx < (unsigned)W_) {
#pragma unroll
                for (int e = 0; e < 8; e++) v[e] = f2bf(sRow[ich * 8 + e][xx]);
            }
            *(short8*)(dst + xp * CG + ich * 8) = v;
        }
        return;
    }

    // ---- weights part ----
    const int tid = (blk - 64 * PD) * 256 + t;
    const int ndw = G_ * KK * 4096;               // 147456
    const int now = G_ * 18 * 2 * 4 * 16 * 8;     // 73728
    if (tid < ndw) {
        const int e  = tid & 7;
        const int nn = (tid >> 3) & 15;
        const int q  = (tid >> 7) & 3;
        const int kh = (tid >> 9) & 1;
        const int ot = (tid >> 10) & 3;
        const int gk = tid >> 12;
        const int k  = gk % KK;
        const int g  = gk / KK;
        const int o  = ot * 16 + nn;
        const int i  = kh * 32 + q * 8 + e;
        dwE[tid] = f2bf(def_w[((g * CG + o) * CG + i) * KK + k]);
    } else if (tid < ndw + now) {
        const int t2 = tid - ndw;
        const int e  = t2 & 7;
        const int jj = (t2 >> 3) & 15;
        const int q  = (t2 >> 7) & 3;
        const int tm = (t2 >> 9) & 1;
        const int gs = t2 >> 10;
        const int s  = gs % 18;
        const int g  = gs / 18;
        const int j  = tm * 16 + jj;
        const int rc = s >> 1;
        const int i  = (s & 1) * 32 + q * 8 + e;
        owA[t2] = (j < 18) ? f2bf(off_w[((g * 18 + j) * CG + i) * KK + rc]) : (short)0;
    }
}

// ---------------------------------------------------------------------------
// Main fused kernel. Block = (b, g, h) with XCD swizzle. 256 threads, 4 waves.
// ZERO barriers: each wave owns positions [p*16, p*16+16) end-to-end.
//  Phase A: offset conv via MFMA 16x16x32; coords -> pcs[9][64] (own slice).
//  Phase B: per tap: direct 16B bf16 corner loads from xTpad, in-register
//           bilinear interp -> B-fragments, 8x MFMA 16x16x32 into 4 o-tiles.
// ---------------------------------------------------------------------------
__global__ __launch_bounds__(256, 4)
void deform_main(const short* __restrict__ xTpad,
                 const float* __restrict__ off_b,
                 const float* __restrict__ def_b,
                 const short* __restrict__ dwE,
                 const short* __restrict__ owA,
                 float* __restrict__ out)
{
    const int raw = blockIdx.x;
    const int r8  = raw & 7;
    const int h   = (raw >> 3) & 63;
    const int q8  = raw >> 9;
    const int bg  = q8 * 8 + r8;
    const int b   = bg >> 2;
    const int g   = bg & 3;

    __shared__ float2 pcs[KK][64];          // .x = padded py, .y = padded px

    const int t    = threadIdx.x;
    const int lane = t & 63;
    const int p    = t >> 6;          // wave id 0..3
    const int nn   = lane & 15;
    const int q    = lane >> 4;

    const short* xb = xTpad + (size_t)bg * XSLICE;

    // ---------------- Phase A: offset conv (MFMA 16x16x32) ----------------
    {
        const short* owAg = owA + g * 18 * 1024;
        f32x4 oa0 = {0.f, 0.f, 0.f, 0.f};
        f32x4 oa1 = {0.f, 0.f, 0.f, 0.f};
#pragma unroll
        for (int rc = 0; rc < 9; rc++) {
            const int rr = rc / 3;
            const int cc = rc % 3;
            const short* cp = xb + ((h + rr + 1) * PD + (p * 16 + nn + cc + 1)) * CG + q * 8;
            const short8 b0 = *(const short8*)cp;          // s = 2rc   (ih=0)
            const short8 b1 = *(const short8*)(cp + 32);   // s = 2rc+1 (ih=32)
            const int s0 = rc * 2, s1 = rc * 2 + 1;
            const short8 a00 = *(const short8*)(owAg + ((s0 * 2 + 0) * 4 + q) * 128 + nn * 8);
            const short8 a01 = *(const short8*)(owAg + ((s0 * 2 + 1) * 4 + q) * 128 + nn * 8);
            const short8 a10 = *(const short8*)(owAg + ((s1 * 2 + 0) * 4 + q) * 128 + nn * 8);
            const short8 a11 = *(const short8*)(owAg + ((s1 * 2 + 1) * 4 + q) * 128 + nn * 8);
            oa0 = __builtin_amdgcn_mfma_f32_16x16x32_bf16(a00, b0, oa0, 0, 0, 0);
            oa1 = __builtin_amdgcn_mfma_f32_16x16x32_bf16(a01, b0, oa1, 0, 0, 0);
            oa0 = __builtin_amdgcn_mfma_f32_16x16x32_bf16(a10, b1, oa0, 0, 0, 0);
            oa1 = __builtin_amdgcn_mfma_f32_16x16x32_bf16(a11, b1, oa1, 0, 0, 0);
        }
        // C layout: col = nn (position within tile), row = q*4 + reg (j)
        const int n = p * 16 + nn;
#pragma unroll
        for (int reg = 0; reg < 4; reg++) {
            const int j  = q * 4 + reg;
            const int kk = j >> 1;
            const float v = oa0[reg] + off_b[g * 18 + j];
            if ((j & 1) == 0) pcs[kk][n].x = v + (float)(kk / 3) + (float)(h + 1);
            else              pcs[kk][n].y = v + (float)(kk % 3) + (float)(n + 1);
        }
        if (q == 0) {
            pcs[8][n].x = oa1[0] + off_b[g * 18 + 16] + 2.0f + (float)(h + 1);
            pcs[8][n].y = oa1[1] + off_b[g * 18 + 17] + 2.0f + (float)(n + 1);
        }
        // wave p only ever reads pcs[.][p*16 .. p*16+15]: no barrier needed
    }

    // ---------------- Phase B: direct-gather einsum, barrier-free ----------
    const int pos = p * 16 + nn;

    f32x4 acc[4];
#pragma unroll
    for (int ot = 0; ot < 4; ot++) acc[ot] = (f32x4){0.f, 0.f, 0.f, 0.f};

    const short* dwl = dwE + g * KK * 4096 + q * 128 + nn * 8;   // lane-fixed

    for (int k = 0; k < KK; k++) {
        const float2 pc = pcs[k][pos];
        const float yf = floorf(pc.x);
        const float xf = floorf(pc.y);
        const float wy = pc.x - yf;
        const float wx = pc.y - xf;
        int y0 = (int)yf;
        int x0 = (int)xf;
        y0 = (y0 < 0) ? 0 : ((y0 > 66) ? 66 : y0);
        x0 = (x0 < 0) ? 0 : ((x0 > 66) ? 66 : x0);
        const short* cp = xb + (y0 * PD + x0) * CG + q * 8;

        // corner loads: chunk A = channels q*8.., chunk B = channels 32+q*8..
        const uint4 a00 = *(const uint4*)(cp);
        const uint4 a01 = *(const uint4*)(cp + CG);
        const uint4 a10 = *(const uint4*)(cp + PD * CG);
        const uint4 a11 = *(const uint4*)(cp + PD * CG + CG);
        const uint4 b00 = *(const uint4*)(cp + 32);
        const uint4 b01 = *(const uint4*)(cp + CG + 32);
        const uint4 b10 = *(const uint4*)(cp + PD * CG + 32);
        const uint4 b11 = *(const uint4*)(cp + PD * CG + CG + 32);

        const float s00 = (1.0f - wy) * (1.0f - wx);
        const float s01 = (1.0f - wy) * wx;
        const float s10 = wy * (1.0f - wx);
        const float s11 = wy * wx;
        const float2 w00 = make_float2(s00, s00);
        const float2 w01 = make_float2(s01, s01);
        const float2 w10 = make_float2(s10, s10);
        const float2 w11 = make_float2(s11, s11);

        const short8 bf0 = interp8(a00, a01, a10, a11, w00, w01, w10, w11);
        const short8 bf1 = interp8(b00, b01, b10, b11, w00, w01, w10, w11);

        const short* dwk = dwl + k * 4096;
#pragma unroll
        for (int ot = 0; ot < 4; ot++) {
            const short8 af0 = *(const short8*)(dwk + ot * 1024);
            const short8 af1 = *(const short8*)(dwk + ot * 1024 + 512);
            acc[ot] = __builtin_amdgcn_mfma_f32_16x16x32_bf16(af0, bf0, acc[ot], 0, 0, 0);
            acc[ot] = __builtin_amdgcn_mfma_f32_16x16x32_bf16(af1, bf1, acc[ot], 0, 0, 0);
        }
    }

    // ---------------- epilogue ----------------
    // C/D 16x16 layout: col = nn (position), row = q*4 + reg (o within tile)
    float* outb = out + (size_t)(b * 256 + g * 64) * HW + h * W_;
#pragma unroll
    for (int ot = 0; ot < 4; ot++) {
#pragma unroll
        for (int reg = 0; reg < 4; reg++) {
            const int o = ot * 16 + q * 4 + reg;
            outb[(size_t)o * HW + pos] = acc[ot][reg] + def_b[g * 64 + o];
        }
    }
}

// ---------------------------------------------------------------------------
// Fallback (no workspace): round-1-style fused fp32 kernel, known correct.
// ---------------------------------------------------------------------------
__global__ __launch_bounds__(256, 4)
void deform_fallback(const float* __restrict__ x,
                     const float* __restrict__ off_w,
                     const float* __restrict__ off_b,
                     const float* __restrict__ def_w,
                     const float* __restrict__ def_b,
                     float* __restrict__ out)
{
    const int raw = blockIdx.x;
    const int r8  = raw & 7;
    const int h   = (raw >> 3) & 63;
    const int q8  = raw >> 9;
    const int bg  = q8 * 8 + r8;
    const int b   = bg >> 2;
    const int g   = bg & 3;

    __shared__ float pys[KK][W_];
    __shared__ float pxs[KK][W_];
    __shared__ float buf[8192];
    float* red   = buf;
    float* s_lds = buf;
    float* dwTl  = buf + 4096;

    const int t = threadIdx.x;
    const int w = t & 63;
    const int p = t >> 6;

    const float* xg = x + (size_t)(b * 256 + g * 64) * HW;

    float acc[18];
#pragma unroll
    for (int j = 0; j < 18; j++) acc[j] = 0.0f;
    {
        const int i0 = p * 16;
        for (int ii = 0; ii < 16; ii++) {
            const int i = i0 + ii;
            const float* xi = xg + i * HW;
#pragma unroll
            for (int r = 0; r < 3; r++) {
                const int y = h + r - 1;
                if ((unsigned)y >= (unsigned)H_) continue;
#pragma unroll
                for (int c = 0; c < 3; c++) {
                    const int xc = w + c - 1;
                    const float xv = ((unsigned)xc < (unsigned)W_) ? xi[y * W_ + xc] : 0.0f;
#pragma unroll
                    for (int j = 0; j < 18; j++) {
                        const float wv = off_w[((g * 18 + j) * CG + i) * 9 + r * 3 + c];
                        acc[j] = fmaf(wv, xv, acc[j]);
                    }
                }
            }
        }
    }
#pragma unroll
    for (int j = 0; j < 18; j++) red[(p * 18 + j) * 64 + w] = acc[j];
    __syncthreads();
    for (int idx = t; idx < 18 * 64; idx += 256) {
        const int j  = idx >> 6;
        const int ww = idx & 63;
        float v = red[(0 * 18 + j) * 64 + ww] + red[(1 * 18 + j) * 64 + ww]
                + red[(2 * 18 + j) * 64 + ww] + red[(3 * 18 + j) * 64 + ww];
        v += off_b[g * 18 + j];
        const int k = j >> 1;
        if ((j & 1) == 0) pys[k][ww] = v + (float)(k / 3 - 1) + (float)h;
        else              pxs[k][ww] = v + (float)(k % 3 - 1) + (float)ww;
    }
    __syncthreads();

    float facc[16];
#pragma unroll
    for (int qd = 0; qd < 16; qd++) facc[qd] = 0.0f;
    const int w4 = (t & 15) << 2;
    const int o4 = (t >> 4) << 2;

    for (int k = 0; k < KK; k++) {
#pragma unroll
        for (int n = 0; n < 16; n++) {
            const int v = t + 256 * n;
            const int i = v >> 6;
            const int o = v & 63;
            dwTl[v] = def_w[((g * CG + o) * CG + i) * KK + k];
        }
        const float py  = pys[k][w];
        const float px  = pxs[k][w];
        const float y0f = floorf(py);
        const float x0f = floorf(px);
        const float wy  = py - y0f;
        const float wx  = px - x0f;
        const int   y0  = (int)y0f;
        const int   x0  = (int)x0f;
        const float w00 = (1.0f - wy) * (1.0f - wx);
        const float w01 = (1.0f - wy) * wx;
        const float w10 = wy * (1.0f - wx);
        const float w11 = wy * wx;
        const bool vy0 = (unsigned)y0       < (unsigned)H_;
        const bool vy1 = (unsigned)(y0 + 1) < (unsigned)H_;
        const bool vx0 = (unsigned)x0       < (unsigned)W_;
        const bool vx1 = (unsigned)(x0 + 1) < (unsigned)W_;
        const int a00 = y0 * W_ + x0;
#pragma unroll
        for (int n = 0; n < 16; n++) {
            const int i = (n << 2) + p;
            const float* xi = xg + i * HW;
            const float v00 = (vy0 && vx0) ? xi[a00]          : 0.0f;
            const float v01 = (vy0 && vx1) ? xi[a00 + 1]      : 0.0f;
            const float v10 = (vy1 && vx0) ? xi[a00 + W_]     : 0.0f;
            const float v11 = (vy1 && vx1) ? xi[a00 + W_ + 1] : 0.0f;
            s_lds[i * 64 + w] = w00 * v00 + w01 * v01 + w10 * v10 + w11 * v11;
        }
        __syncthreads();
#pragma unroll 4
        for (int i = 0; i < CG; i++) {
            const float4 sv = *(const float4*)&s_lds[i * 64 + w4];
            const float4 dv = *(const float4*)&dwTl[i * 64 + o4];
            facc[0]  = fmaf(dv.x, sv.x, facc[0]);
            facc[1]  = fmaf(dv.x, sv.y, facc[1]);
            facc[2]  = fmaf(dv.x, sv.z, facc[2]);
            facc[3]  = fmaf(dv.x, sv.w, facc[3]);
            facc[4]  = fmaf(dv.y, sv.x, facc[4]);
            facc[5]  = fmaf(dv.y, sv.y, facc[5]);
            facc[6]  = fmaf(dv.y, sv.z, facc[6]);
            facc[7]  = fmaf(dv.y, sv.w, facc[7]);
            facc[8]  = fmaf(dv.z, sv.x, facc[8]);
            facc[9]  = fmaf(dv.z, sv.y, facc[9]);
            facc[10] = fmaf(dv.z, sv.z, facc[10]);
            facc[11] = fmaf(dv.z, sv.w, facc[11]);
            facc[12] = fmaf(dv.w, sv.x, facc[12]);
            facc[13] = fmaf(dv.w, sv.y, facc[13]);
            facc[14] = fmaf(dv.w, sv.z, facc[14]);
            facc[15] = fmaf(dv.w, sv.w, facc[15]);
        }
        __syncthreads();
    }

    float* outp = out + (size_t)(b * 256 + g * 64) * HW + h * W_;
#pragma unroll
    for (int oo = 0; oo < 4; oo++) {
        const int o = o4 + oo;
        const float bias = def_b[g * 64 + o];
        float4 r;
        r.x = facc[oo * 4 + 0] + bias;
        r.y = facc[oo * 4 + 1] + bias;
        r.z = facc[oo * 4 + 2] + bias;
        r.w = facc[oo * 4 + 3] + bias;
        *(float4*)&outp[o * HW + w4] = r;
    }
}

// ---------------------------------------------------------------------------
extern "C" void kernel_launch(void* const* d_in, const int* in_sizes, int n_in,
                              void* d_out, int out_size, void* d_ws, size_t ws_size,
                              hipStream_t stream)
{
    (void)in_sizes; (void)n_in; (void)out_size;
    const float* x     = (const float*)d_in[0];
    const float* off_w = (const float*)d_in[1];
    const float* off_b = (const float*)d_in[2];
    const float* def_w = (const float*)d_in[3];
    const float* def_b = (const float*)d_in[4];
    float* out = (float*)d_out;

    const size_t xT_bytes  = (size_t)B_ * G_ * XSLICE * 2;     // 37,879,808
    const size_t dw_bytes  = (size_t)G_ * KK * 4096 * 2;       // 294,912
    const size_t ow_bytes  = (size_t)G_ * 18 * 1024 * 2;       // 147,456
    const size_t need = xT_bytes + dw_bytes + ow_bytes;

    const int nblk   = B_ * G_ * H_;                     // 4096
    const int nprepw = (G_ * KK * 4096 + G_ * 18 * 1024 + 255) / 256;  // 864
    const int nprep  = 64 * PD + nprepw;

    if (ws_size >= need) {
        short* xTpad = (short*)d_ws;
        short* dwE   = (short*)((char*)d_ws + xT_bytes);
        short* owA   = (short*)((char*)d_ws + xT_bytes + dw_bytes);
        prep_all<<<nprep, 256, 0, stream>>>(x, off_w, def_w, xTpad, dwE, owA);
        deform_main<<<nblk, 256, 0, stream>>>(xTpad, off_b, def_b, dwE, owA, out);
    } else {
        deform_fallback<<<nblk, 256, 0, stream>>>(x, off_w, off_b, def_w, def_b, out);
    }
}